// Round 5
// baseline (9523.499 us; speedup 1.0000x reference)
//
#include <hip/hip_runtime.h>

typedef unsigned short u16;
typedef unsigned int u32;
typedef __attribute__((ext_vector_type(4))) float f32x4;
typedef __attribute__((ext_vector_type(8))) short bfrag;   // 8 x bf16 bits
typedef __attribute__((ext_vector_type(8))) unsigned short us8;

// ---------- helpers ----------
__device__ __forceinline__ u16 f2bf(float f) {
    union { float f; unsigned u; } v; v.f = f;
    unsigned r = v.u + 0x7fffu + ((v.u >> 16) & 1u);   // RNE
    return (u16)(r >> 16);
}
__device__ __forceinline__ float sigm(float x) { return 1.0f / (1.0f + __expf(-x)); }
__device__ __forceinline__ float tanh_(float x) { return 1.0f - 2.0f / (__expf(2.0f * x) + 1.0f); }

// ---------- phase A: convert x to bf16 ----------
__global__ __launch_bounds__(256) void pack_x(const float* __restrict__ x, u16* __restrict__ xbf) {
    int gid = blockIdx.x * 256 + threadIdx.x;          // 2,097,152 threads, 8 elems each
    size_t base = (size_t)gid * 8;
    const float4* xv = (const float4*)(x + base);
    float4 a = xv[0], b = xv[1];
    us8 r;
    r[0] = f2bf(a.x); r[1] = f2bf(a.y); r[2] = f2bf(a.z); r[3] = f2bf(a.w);
    r[4] = f2bf(b.x); r[5] = f2bf(b.y); r[6] = f2bf(b.z); r[7] = f2bf(b.w);
    *(us8*)(xbf + base) = r;
}

// ---------- phase A: zero h tile buffers + flags (ws poisoned every call) ----------
__global__ __launch_bounds__(256) void zero_ctl(uint4* __restrict__ p) {
    int gid = blockIdx.x * 256 + threadIdx.x;          // zero 263,168 B = 16,448 uint4
    if (gid < 16448) p[gid] = make_uint4(0u, 0u, 0u, 0u);
}

// ---------- phase A: pack W into MFMA B-fragment layout ----------
// packed[dir][half][ntile(128)][ks(16)][lane(64)][8 bf16]
// element (nt,ks,lane,j) = W[half*512 + ks*32 + (lane>>4)*8 + j][nt*16 + (lane&15)]
__global__ __launch_bounds__(256) void pack_w(const float* __restrict__ Wf, const float* __restrict__ Wb,
                                              u16* __restrict__ wxp, u16* __restrict__ whp) {
    int g = blockIdx.x * 256 + threadIdx.x;            // 524,288 threads
    int lane = g & 63; g >>= 6;
    int ks = g & 15;  g >>= 4;
    int nt = g & 127; g >>= 7;
    int half = g & 1;
    int dir = g >> 1;
    const float* W = dir ? Wb : Wf;
    u16* dst = (half ? whp : wxp) + (size_t)dir * 1048576;
    int rowb = half * 512 + ks * 32 + (lane >> 4) * 8;
    int col  = nt * 16 + (lane & 15);
    us8 v;
#pragma unroll
    for (int j = 0; j < 8; ++j) v[j] = f2bf(W[(size_t)(rowb + j) * 2048 + col]);
    *(us8*)(dst + ((size_t)(nt * 16 + ks) * 64 + lane) * 8) = v;
}

// ---------- phase B: wave-autonomous recurrence, tile-coalesced L3 h exchange ----------
// 256 blocks x 64 threads: bid = dir(1) x w(2: batch rows [16w,+16)) x j(5: hcols [16j,+16)).
// 8 independent sync groups (dir,w) of 32 waves — batch-row groups never interact.
// h exchanged as contiguous 512B row-major 16x16 tiles: hb[dir][phase][w][j][16][16] (u16).
// Producer: LDS-stage 512B -> ONE 32-lane global_store_dwordx4 sc1. Consumer: 16 coalesced
// 1KB global_load_dwordx4 sc1 (tile layout == MFMA A-fragment permutation within 1KB pair).
// x-part(t+1) MFMAs run between h-load issue and vmcnt(0) to hide the L3 latency.
__global__ __launch_bounds__(64, 1) void rnn_all(const u16* __restrict__ wxp, const u16* __restrict__ whp,
                                                 const u16* __restrict__ xbf,
                                                 const float* __restrict__ b_fw, const float* __restrict__ b_bw,
                                                 u16* __restrict__ hbuf, unsigned* __restrict__ ctrl,
                                                 float* __restrict__ out) {
    __shared__ u16 tile_lds[256];                       // 512 B staging
    const int lane = threadIdx.x & 63;
    const int bid = blockIdx.x;
    const int dir = bid >> 7, w = (bid >> 5) & 3, j = bid & 31;
    const int l15 = lane & 15, lhi = lane >> 4;
    const int m0 = w * 16;
    const u16* wxs = wxp + (size_t)dir * 1048576;
    const u16* whs = whp + (size_t)dir * 1048576;
    const float* bias = dir ? b_bw : b_fw;
    float bv[4];
#pragma unroll
    for (int g = 0; g < 4; ++g) bv[g] = bias[g * 512 + j * 16 + l15];

    const u16* xb = xbf + (size_t)(m0 + l15) * 262144 + lhi * 8;   // x[b][t][k]
    unsigned* flagw = ctrl + dir * 128 + w * 32;

    // tile-buffer bases (u16 units): (dir,phase,w) pane = 8192 u16 = 16 KB (32 tiles x 256)
    u16* pane[2];
    pane[0] = hbuf + (size_t)((dir * 2 + 0) * 4 + w) * 8192;
    pane[1] = hbuf + (size_t)((dir * 2 + 1) * 4 + w) * 8192;
    const size_t rd_off = (size_t)(lhi >> 1) * 256 + l15 * 16 + (lhi & 1) * 8;  // within tile-pair
    const size_t wr_off = (size_t)j * 256 + (lane & 31) * 8;                    // producer, 32 lanes

    float c[4] = {0.f, 0.f, 0.f, 0.f};
    const int row = m0 + lhi * 4;            // first of 4 batch rows this thread finalizes
    const int hcol = j * 16 + l15;
    float* outb = out + (size_t)row * 524288 + dir * 512 + hcol;    // + r*524288 + t*1024

    // prologue: acc = bias + x-part(t0)
    f32x4 acc[4], accN[4];
#pragma unroll
    for (int g = 0; g < 4; ++g) acc[g] = (f32x4){bv[g], bv[g], bv[g], bv[g]};
    {
        const u16* xt = xb + (dir ? 511 : 0) * 512;
#pragma unroll
        for (int ks = 0; ks < 16; ++ks) {
            bfrag ax = *(const bfrag*)(xt + ks * 32);
#pragma unroll
            for (int g = 0; g < 4; ++g)
                acc[g] = __builtin_amdgcn_mfma_f32_16x16x32_bf16(
                    ax, *(const bfrag*)&wxs[(size_t)(g * 32 + j) * 8192 + ks * 512 + lane * 8], acc[g], 0, 0, 0);
        }
    }

#pragma unroll 1
    for (int s = 0; s < 512; ++s) {
        const int t = dir ? (511 - s) : s;

        // A. wait for all 32 producers of my row-group to publish h(s-1)
        if (s) {
            unsigned f;
            do {
                f = 0xffffffffu;
                if (lane < 32)
                    f = __hip_atomic_load(&flagw[lane], __ATOMIC_RELAXED, __HIP_MEMORY_SCOPE_AGENT);
            } while (__any((int)(f < (unsigned)s)));
        }

        // B. issue 16 coalesced 1KB h-tile loads (agent scope -> L3)
        const u16* hrd = pane[s & 1] + rd_off;
        bfrag ah[16];
#pragma unroll
        for (int ks = 0; ks < 16; ++ks)
            asm volatile("global_load_dwordx4 %0, %1, off offset:%2 sc1"
                         : "=&v"(ah[ks]) : "v"(hrd + (ks & ~3) * 512), "i"((ks & 3) * 1024) : "memory");

        // C. x-part for step s+1 into accN — hides h-load L3 latency under L2-hot MFMAs
        if (s < 511) {
            const int tn = dir ? (510 - s) : (s + 1);
#pragma unroll
            for (int g = 0; g < 4; ++g) accN[g] = (f32x4){bv[g], bv[g], bv[g], bv[g]};
            const u16* xt = xb + tn * 512;
#pragma unroll
            for (int ks = 0; ks < 16; ++ks) {
                bfrag ax = *(const bfrag*)(xt + ks * 32);
#pragma unroll
                for (int g = 0; g < 4; ++g)
                    accN[g] = __builtin_amdgcn_mfma_f32_16x16x32_bf16(
                        ax, *(const bfrag*)&wxs[(size_t)(g * 32 + j) * 8192 + ks * 512 + lane * 8], accN[g], 0, 0, 0);
            }
        }

        // D. h loads retired (rule #18: waitcnt + sched_barrier before register use)
        asm volatile("s_waitcnt vmcnt(0)" ::: "memory");
        __builtin_amdgcn_sched_barrier(0);

        // E. h-part MFMAs (Wh B-fragments stream from L1/L2, never invalidated)
#pragma unroll
        for (int ks = 0; ks < 16; ++ks)
#pragma unroll
            for (int g = 0; g < 4; ++g)
                acc[g] = __builtin_amdgcn_mfma_f32_16x16x32_bf16(
                    ah[ks], *(const bfrag*)&whs[(size_t)(g * 32 + j) * 8192 + ks * 512 + lane * 8], acc[g], 0, 0, 0);

        // F. finalize gates i,j,f,o = acc[0..3]; stage h tile in LDS
        float hv[4];
#pragma unroll
        for (int r = 0; r < 4; ++r) {
            float cn = sigm(acc[2][r] + 1.0f) * c[r] + sigm(acc[0][r]) * tanh_(acc[1][r]);
            c[r] = cn;
            float h = sigm(acc[3][r]) * tanh_(cn);
            hv[r] = h;
            tile_lds[(lhi * 4 + r) * 16 + l15] = f2bf(h);   // tile[row][col]
        }

        // G. publish: ONE contiguous 512B sc1 store (32 lanes), drain, then flag
        if (s < 511) {
            asm volatile("s_waitcnt lgkmcnt(0)" ::: "memory");
            __builtin_amdgcn_sched_barrier(0);
            if (lane < 32) {
                us8 v = *(const us8*)&tile_lds[lane * 8];
                asm volatile("global_store_dwordx4 %0, %1, off sc1"
                             :: "v"(pane[(s & 1) ^ 1] + wr_off), "v"(v) : "memory");
            }
            asm volatile("s_waitcnt vmcnt(0)" ::: "memory");
            if (lane == 0) {
                unsigned fv = (unsigned)(s + 1);
                asm volatile("global_store_dword %0, %1, off sc1"
                             :: "v"(flagw + j), "v"(fv) : "memory");
            }
        }

        // H. out stores (plain write-back, off the critical path)
#pragma unroll
        for (int r = 0; r < 4; ++r)
            outb[(size_t)r * 524288 + t * 1024] = hv[r];

        // I. rotate accumulators
#pragma unroll
        for (int g = 0; g < 4; ++g) acc[g] = accN[g];
    }
}

// ---------- launcher ----------
extern "C" void kernel_launch(void* const* d_in, const int* in_sizes, int n_in,
                              void* d_out, int out_size, void* d_ws, size_t ws_size,
                              hipStream_t stream) {
    (void)in_sizes; (void)n_in; (void)out_size;
    const float* x  = (const float*)d_in[0];
    const float* Wf = (const float*)d_in[1];
    const float* bf = (const float*)d_in[2];
    const float* Wb = (const float*)d_in[3];
    const float* bb = (const float*)d_in[4];
    float* out = (float*)d_out;

    // workspace layout (bytes), total 42,209,280
    const size_t o_wx  = 0;                    //  4,194,304  packed W_x (2 dirs)
    const size_t o_wh  = 4194304;              //  4,194,304  packed W_h (2 dirs)
    const size_t o_hb  = 8388608;              //    262,144  h tiles [dir][phase][w][j][256]
    const size_t o_ct  = 8650752;              //      1,024  flags [dir][w][j] (+pad)
    const size_t o_xbf = 8654848;              // 33,554,432  x in bf16
    const size_t need  = o_xbf + 33554432;
    if (ws_size < need) return;

    char* ws = (char*)d_ws;
    u16* wxp = (u16*)(ws + o_wx);
    u16* whp = (u16*)(ws + o_wh);
    u16* hb  = (u16*)(ws + o_hb);
    unsigned* ctl = (unsigned*)(ws + o_ct);
    u16* xbf = (u16*)(ws + o_xbf);

    hipLaunchKernelGGL(pack_x, dim3(8192), dim3(256), 0, stream, x, xbf);
    hipLaunchKernelGGL(zero_ctl, dim3(65), dim3(256), 0, stream, (uint4*)(ws + o_hb));
    hipLaunchKernelGGL(pack_w, dim3(2048), dim3(256), 0, stream, Wf, Wb, wxp, whp);
    hipLaunchKernelGGL(rnn_all, dim3(256), dim3(64), 0, stream,
                       wxp, whp, xbf, bf, bb, hb, ctl, out);
}

// Round 7
// 1955.463 us; speedup vs baseline: 4.8702x; 4.8702x over previous
//
#include <hip/hip_runtime.h>

typedef unsigned short u16;
typedef unsigned int u32;
typedef __attribute__((ext_vector_type(4))) float f32x4;
typedef __attribute__((ext_vector_type(8))) short bfrag;   // 8 x bf16 bits
typedef __attribute__((ext_vector_type(8))) unsigned short us8;

// ---------- helpers ----------
__device__ __forceinline__ u16 f2bf(float f) {
    union { float f; unsigned u; } v; v.f = f;
    unsigned r = v.u + 0x7fffu + ((v.u >> 16) & 1u);   // RNE
    return (u16)(r >> 16);
}
__device__ __forceinline__ float sigm(float x) { return 1.0f / (1.0f + __expf(-x)); }
__device__ __forceinline__ float tanh_(float x) { return 1.0f - 2.0f / (__expf(2.0f * x) + 1.0f); }

// ---------- phase A: convert x to bf16 ----------
__global__ __launch_bounds__(256) void pack_x(const float* __restrict__ x, u16* __restrict__ xbf) {
    int gid = blockIdx.x * 256 + threadIdx.x;          // 2,097,152 threads, 8 elems each
    size_t base = (size_t)gid * 8;
    const float4* xv = (const float4*)(x + base);
    float4 a = xv[0], b = xv[1];
    us8 r;
    r[0] = f2bf(a.x); r[1] = f2bf(a.y); r[2] = f2bf(a.z); r[3] = f2bf(a.w);
    r[4] = f2bf(b.x); r[5] = f2bf(b.y); r[6] = f2bf(b.z); r[7] = f2bf(b.w);
    *(us8*)(xbf + base) = r;
}

// ---------- phase A: zero h panes + flags (ws poisoned every call) ----------
__global__ __launch_bounds__(256) void zero_ctl(uint4* __restrict__ p) {
    int gid = blockIdx.x * 256 + threadIdx.x;          // zero 263,168 B = 16,448 uint4
    if (gid < 16448) p[gid] = make_uint4(0u, 0u, 0u, 0u);
}

// ---------- phase A: pack W into MFMA B-fragment layout ----------
// packed[dir][half][ntile(128)][ks(16)][lane(64)][8 bf16]
// element (nt,ks,lane,j) = W[half*512 + ks*32 + (lane>>4)*8 + j][nt*16 + (lane&15)]
__global__ __launch_bounds__(256) void pack_w(const float* __restrict__ Wf, const float* __restrict__ Wb,
                                              u16* __restrict__ wxp, u16* __restrict__ whp) {
    int g = blockIdx.x * 256 + threadIdx.x;            // 524,288 threads
    int lane = g & 63; g >>= 6;
    int ks = g & 15;  g >>= 4;
    int nt = g & 127; g >>= 7;
    int half = g & 1;
    int dir = g >> 1;
    const float* W = dir ? Wb : Wf;
    u16* dst = (half ? whp : wxp) + (size_t)dir * 1048576;
    int rowb = half * 512 + ks * 32 + (lane >> 4) * 8;
    int col  = nt * 16 + (lane & 15);
    us8 v;
#pragma unroll
    for (int j = 0; j < 8; ++j) v[j] = f2bf(W[(size_t)(rowb + j) * 2048 + col]);
    *(us8*)(dst + ((size_t)(nt * 16 + ks) * 64 + lane) * 8) = v;
}

// ---------- phase B: recurrence. 256 blocks x 256 thr (4 waves = 4 gates). ----------
// Role: dir = bid>>7, w = (bid>>5)&3 (batch rows [16w,+16)), jb = bid&31 (hcols [16jb,+16)).
// Per wave (gate g=widx): Wx,Wh fragment slices live in 128 VGPRs (loaded once);
// x(t+1) prefetched into 64 VGPRs. h exchanged via sc1/L3 in MFMA A-fragment layout:
// pane[dir][phase][w] = 16KB; producer's 16x16 tile = contiguous 512B chunk at jb*512.
// Consumer: 4 waves coop-load 4x1KB each -> LDS; gates combined via 3KB LDS; wave 0
// finalizes, publishes 512B tile + monotonic flag. 3 raw s_barriers per step.
__global__ __launch_bounds__(256, 1) void rnn_all(const u16* __restrict__ wxp, const u16* __restrict__ whp,
                                                  const u16* __restrict__ xbf,
                                                  const float* __restrict__ b_fw, const float* __restrict__ b_bw,
                                                  u16* __restrict__ hbuf, unsigned* __restrict__ ctrl,
                                                  float* __restrict__ out) {
    __shared__ u16 h_lds[8192];       // 16 KB: h(s-1) A-frag layout [ks(16)][lane(64)][8]
    __shared__ float comb[768];       // 3 KB: gate j/f/o partials from waves 1..3
    __shared__ u16 stage[256];        // 512 B: producer tile staging
    const int tid = threadIdx.x;
    const int widx = tid >> 6, lane = tid & 63, l15 = lane & 15, lhi = lane >> 4;
    const int bid = blockIdx.x;
    const int dir = bid >> 7, w = (bid >> 5) & 3, jb = bid & 31;

    const u16* wxs = wxp + (size_t)dir * 1048576;
    const u16* whs = whp + (size_t)dir * 1048576;

    // one-time: weight fragments into registers (gate widx, hcols [16jb,+16))
    bfrag wxr[16], whr[16];
#pragma unroll
    for (int ks = 0; ks < 16; ++ks) {
        wxr[ks] = *(const bfrag*)&wxs[(size_t)(widx * 32 + jb) * 8192 + ks * 512 + lane * 8];
        whr[ks] = *(const bfrag*)&whs[(size_t)(widx * 32 + jb) * 8192 + ks * 512 + lane * 8];
    }
    const float* bias = dir ? b_bw : b_fw;
    const float bv = bias[widx * 512 + jb * 16 + l15];

    const u16* xrow = xbf + (size_t)(w * 16 + l15) * 262144 + lhi * 8;   // x[b][t][k]
    u16* hb0 = hbuf + (size_t)((dir * 2 + 0) * 4 + w) * 8192;            // pane phase 0
    u16* hb1 = hbuf + (size_t)((dir * 2 + 1) * 4 + w) * 8192;            // pane phase 1
    unsigned* flagw = ctrl + (dir * 4 + w) * 32;

    float c[4] = {0.f, 0.f, 0.f, 0.f};

    // prologue: xr = x(t0); acc = bias + x-part(t0); xr = x(t1)
    bfrag xr[16];
    {
        const u16* xt = xrow + (size_t)(dir ? 511 : 0) * 512;
#pragma unroll
        for (int ks = 0; ks < 16; ++ks) xr[ks] = *(const bfrag*)(xt + ks * 32);
    }
    f32x4 acc = {bv, bv, bv, bv};
#pragma unroll
    for (int ks = 0; ks < 16; ++ks)
        acc = __builtin_amdgcn_mfma_f32_16x16x32_bf16(xr[ks], wxr[ks], acc, 0, 0, 0);
    {
        const u16* xt = xrow + (size_t)(dir ? 510 : 1) * 512;
#pragma unroll
        for (int ks = 0; ks < 16; ++ks) xr[ks] = *(const bfrag*)(xt + ks * 32);
    }

#pragma unroll 1
    for (int s = 0; s < 512; ++s) {
        const int t = dir ? (511 - s) : s;

        // A. wave 0 polls all 32 producer flags >= s (sc1 loads straight from L3)
        if (widx == 0 && s) {
            const unsigned* fp = flagw + (lane & 31);
            unsigned fv;
            do {
                asm volatile("global_load_dword %0, %1, off sc1\n\ts_waitcnt vmcnt(0)"
                             : "=&v"(fv) : "v"(fp) : "memory");
                if (lane >= 32) fv = (unsigned)s;
            } while (__any((int)(fv < (unsigned)s)));
        }
        __builtin_amdgcn_s_barrier();                 // barA: release all waves
        __builtin_amdgcn_sched_barrier(0);

        // B. coop h(s-1) load: wave widx pulls ks in [4*widx, +4) — 4 contiguous 1KB loads
        const u16* pr = (s & 1 ? hb1 : hb0) + widx * 2048 + lane * 8;
        bfrag t0, t1, t2, t3;
        asm volatile("global_load_dwordx4 %0, %4, off sc1\n\t"
                     "global_load_dwordx4 %1, %4, off offset:1024 sc1\n\t"
                     "global_load_dwordx4 %2, %4, off offset:2048 sc1\n\t"
                     "global_load_dwordx4 %3, %4, off offset:3072 sc1"
                     : "=&v"(t0), "=&v"(t1), "=&v"(t2), "=&v"(t3) : "v"(pr) : "memory");

        // C. x-part for NEXT step — pure-register MFMAs hide the h-load latency
        f32x4 aN = {bv, bv, bv, bv};
#pragma unroll
        for (int ks = 0; ks < 16; ++ks)
            aN = __builtin_amdgcn_mfma_f32_16x16x32_bf16(xr[ks], wxr[ks], aN, 0, 0, 0);

        // D. h loads retired -> LDS stage -> barrier
        asm volatile("s_waitcnt vmcnt(0)" ::: "memory");
        __builtin_amdgcn_sched_barrier(0);
        *(bfrag*)&h_lds[widx * 2048 +        lane * 8] = t0;
        *(bfrag*)&h_lds[widx * 2048 +  512 + lane * 8] = t1;
        *(bfrag*)&h_lds[widx * 2048 + 1024 + lane * 8] = t2;
        *(bfrag*)&h_lds[widx * 2048 + 1536 + lane * 8] = t3;
        asm volatile("s_waitcnt lgkmcnt(0)" ::: "memory");
        __builtin_amdgcn_s_barrier();                 // barB: h(s-1) staged
        __builtin_amdgcn_sched_barrier(0);

        // E. h-part MFMAs (A-frags from LDS, B-frags from registers)
#pragma unroll
        for (int ks = 0; ks < 16; ++ks) {
            bfrag ah = *(const bfrag*)&h_lds[ks * 512 + lane * 8];
            acc = __builtin_amdgcn_mfma_f32_16x16x32_bf16(ah, whr[ks], acc, 0, 0, 0);
        }

        // F. waves 1..3 deposit gate partials (j,f,o)
        if (widx) {
#pragma unroll
            for (int r = 0; r < 4; ++r)
                comb[(widx - 1) * 256 + (lhi * 4 + r) * 16 + l15] = acc[r];
        }
        asm volatile("s_waitcnt lgkmcnt(0)" ::: "memory");
        __builtin_amdgcn_s_barrier();                 // barC: gates ready
        __builtin_amdgcn_sched_barrier(0);

        // G. wave 0: finalize, publish tile + flag, out stores
        if (widx == 0) {
            float hv[4];
#pragma unroll
            for (int r = 0; r < 4; ++r) {
                float jv = comb[      (lhi * 4 + r) * 16 + l15];
                float fg = comb[256 + (lhi * 4 + r) * 16 + l15];
                float ov = comb[512 + (lhi * 4 + r) * 16 + l15];
                float cn = sigm(fg + 1.0f) * c[r] + sigm(acc[r]) * tanh_(jv);
                c[r] = cn;
                hv[r] = sigm(ov) * tanh_(cn);
                stage[(l15 >> 3) * 128 + (lhi * 4 + r) * 8 + (l15 & 7)] = f2bf(hv[r]);
            }
            asm volatile("s_waitcnt lgkmcnt(0)" ::: "memory");
            if (s < 511) {
                u16* pw = (s & 1 ? hb0 : hb1) + jb * 256 + (lane & 31) * 8;
                if (lane < 32) {
                    us8 v = *(const us8*)&stage[lane * 8];
                    asm volatile("global_store_dwordx4 %0, %1, off sc1"
                                 :: "v"(pw), "v"(v) : "memory");
                }
                asm volatile("s_waitcnt vmcnt(0)" ::: "memory");
                if (lane == 0) {
                    unsigned pv = (unsigned)(s + 1);
                    asm volatile("global_store_dword %0, %1, off sc1"
                                 :: "v"(flagw + jb), "v"(pv) : "memory");
                }
            }
            float* ob = out + ((size_t)(w * 16 + lhi * 4) * 512 + t) * 1024 + dir * 512 + jb * 16 + l15;
#pragma unroll
            for (int r = 0; r < 4; ++r)
                ob[(size_t)r * 524288] = hv[r];
        }

        // H. refill x prefetch for step s+2 (retires during next step's poll window)
        if (s < 510) {
            const int tn = dir ? (509 - s) : (s + 2);
            const u16* xt = xrow + (size_t)tn * 512;
#pragma unroll
            for (int ks = 0; ks < 16; ++ks) xr[ks] = *(const bfrag*)(xt + ks * 32);
        }
        acc = aN;
    }
}

// ---------- launcher ----------
extern "C" void kernel_launch(void* const* d_in, const int* in_sizes, int n_in,
                              void* d_out, int out_size, void* d_ws, size_t ws_size,
                              hipStream_t stream) {
    (void)in_sizes; (void)n_in; (void)out_size;
    const float* x  = (const float*)d_in[0];
    const float* Wf = (const float*)d_in[1];
    const float* bf = (const float*)d_in[2];
    const float* Wb = (const float*)d_in[3];
    const float* bb = (const float*)d_in[4];
    float* out = (float*)d_out;

    // workspace layout (bytes), total 42,209,280
    const size_t o_wx  = 0;                    //  4,194,304  packed W_x (2 dirs)
    const size_t o_wh  = 4194304;              //  4,194,304  packed W_h (2 dirs)
    const size_t o_hb  = 8388608;              //    262,144  h panes [dir][phase][w] 16KB each
    const size_t o_ct  = 8650752;              //      1,024  flags [dir][w][32]
    const size_t o_xbf = 8654848;              // 33,554,432  x in bf16
    const size_t need  = o_xbf + 33554432;
    if (ws_size < need) return;

    char* ws = (char*)d_ws;
    u16* wxp = (u16*)(ws + o_wx);
    u16* whp = (u16*)(ws + o_wh);
    u16* hb  = (u16*)(ws + o_hb);
    unsigned* ctl = (unsigned*)(ws + o_ct);
    u16* xbf = (u16*)(ws + o_xbf);

    hipLaunchKernelGGL(pack_x, dim3(8192), dim3(256), 0, stream, x, xbf);
    hipLaunchKernelGGL(zero_ctl, dim3(65), dim3(256), 0, stream, (uint4*)(ws + o_hb));
    hipLaunchKernelGGL(pack_w, dim3(2048), dim3(256), 0, stream, Wf, Wb, wxp, whp);
    hipLaunchKernelGGL(rnn_all, dim3(256), dim3(256), 0, stream,
                       wxp, whp, xbf, bf, bb, hb, ctl, out);
}